// Round 1
// baseline (766.894 us; speedup 1.0000x reference)
//
#include <hip/hip_runtime.h>
#include <hip/hip_bf16.h>
#include <math.h>

// ---------------------------------------------------------------------------
// VariationalGATEncoder: 3x GATConv (single head, PyG semantics)
//   layer1: x[50000,256] -> h[50000,256], relu
//   mu:     h -> [50000,128]
//   logstd: h -> [50000,128]
// Same edge set for all layers -> build CSR (by dst) once, reuse 3x.
// Aggregation uses online softmax per dst node (one wave per node), so edge
// logits are never materialized and there are no atomics on feature vectors.
// ---------------------------------------------------------------------------

#define NNODES 50000

// ---------------- CSR build ----------------

__global__ void count_edges(const int* __restrict__ dst, int E, int* __restrict__ cnt) {
    int e = blockIdx.x * blockDim.x + threadIdx.x;
    if (e < E) atomicAdd(&cnt[dst[e]], 1);
}

// Single-block exclusive scan of cnt[0..N-1] -> row_start[0..N]
__global__ void scan_kernel(const int* __restrict__ cnt, int* __restrict__ row_start, int N) {
    __shared__ int tmp[1024];
    __shared__ int carry_s;
    int t = threadIdx.x;
    if (t == 0) carry_s = 0;
    __syncthreads();
    for (int base = 0; base < N; base += 1024) {
        int v = (base + t < N) ? cnt[base + t] : 0;
        tmp[t] = v;
        __syncthreads();
        // Hillis-Steele inclusive scan
        for (int off = 1; off < 1024; off <<= 1) {
            int add = (t >= off) ? tmp[t - off] : 0;
            __syncthreads();
            tmp[t] += add;
            __syncthreads();
        }
        if (base + t < N) row_start[base + t] = carry_s + tmp[t] - v;
        int total = tmp[1023];
        __syncthreads();            // all reads of carry_s/tmp done
        if (t == 0) carry_s += total;
        __syncthreads();            // new carry visible; tmp reusable
    }
    if (t == 0) row_start[N] = carry_s;   // == E
}

__global__ void scatter_edges(const int* __restrict__ src, const int* __restrict__ dst, int E,
                              const int* __restrict__ row_start, int* __restrict__ cursor,
                              int* __restrict__ sperm) {
    int e = blockIdx.x * blockDim.x + threadIdx.x;
    if (e < E) {
        int d = dst[e];
        int pos = row_start[d] + atomicAdd(&cursor[d], 1);
        sperm[pos] = src[e];
    }
}

// ---------------- SGEMM: C[N,Cout] = A[N,K] @ B[K,Cout] ----------------
// 64x64 tile, BK=16, 256 threads, 4x4 per thread.

__global__ __launch_bounds__(256) void sgemm(const float* __restrict__ A,
                                             const float* __restrict__ B,
                                             float* __restrict__ C_,
                                             int N, int K, int Cout) {
    __shared__ float As[64][16];
    __shared__ float Bs[16][64];
    int tid = threadIdx.x;
    int tx = tid & 15, ty = tid >> 4;
    int rowBase = blockIdx.x * 64, colBase = blockIdx.y * 64;
    float acc[4][4] = {};
    for (int k0 = 0; k0 < K; k0 += 16) {
        {   // load A tile: 64x16, one float4 per thread
            int r = tid >> 2;
            int c4 = (tid & 3) * 4;
            int gr = rowBase + r;
            float4 v = make_float4(0.f, 0.f, 0.f, 0.f);
            if (gr < N) v = *(const float4*)(A + (size_t)gr * K + k0 + c4);
            *(float4*)(&As[r][c4]) = v;
        }
        {   // load B tile: 16x64
            int r = tid >> 4;
            int c4 = (tid & 15) * 4;
            float4 v = *(const float4*)(B + (size_t)(k0 + r) * Cout + colBase + c4);
            *(float4*)(&Bs[r][c4]) = v;
        }
        __syncthreads();
#pragma unroll
        for (int k = 0; k < 16; k++) {
            float a[4], b[4];
#pragma unroll
            for (int i = 0; i < 4; i++) a[i] = As[ty * 4 + i][k];
#pragma unroll
            for (int j = 0; j < 4; j++) b[j] = Bs[k][tx * 4 + j];
#pragma unroll
            for (int i = 0; i < 4; i++)
#pragma unroll
                for (int j = 0; j < 4; j++)
                    acc[i][j] += a[i] * b[j];
        }
        __syncthreads();
    }
#pragma unroll
    for (int i = 0; i < 4; i++) {
        int gr = rowBase + ty * 4 + i;
        if (gr < N) {
            float4 v = make_float4(acc[i][0], acc[i][1], acc[i][2], acc[i][3]);
            *(float4*)(C_ + (size_t)gr * Cout + colBase + tx * 4) = v;
        }
    }
}

// ---------------- per-node attention logits ----------------

template <int C>
__global__ __launch_bounds__(256) void scores_kernel(const float* __restrict__ h,
                                                     const float* __restrict__ a_src,
                                                     const float* __restrict__ a_dst,
                                                     float* __restrict__ s_src,
                                                     float* __restrict__ s_dst, int N) {
    int wave = threadIdx.x >> 6, lane = threadIdx.x & 63;
    int row = blockIdx.x * 4 + wave;
    if (row >= N) return;
    const float* hr = h + (size_t)row * C;
    float ss = 0.f, sd = 0.f;
    if constexpr (C == 256) {
        float4 v = ((const float4*)hr)[lane];
        float4 as = ((const float4*)a_src)[lane];
        float4 ad = ((const float4*)a_dst)[lane];
        ss = v.x * as.x + v.y * as.y + v.z * as.z + v.w * as.w;
        sd = v.x * ad.x + v.y * ad.y + v.z * ad.z + v.w * ad.w;
    } else {
        float2 v = ((const float2*)hr)[lane];
        float2 as = ((const float2*)a_src)[lane];
        float2 ad = ((const float2*)a_dst)[lane];
        ss = v.x * as.x + v.y * as.y;
        sd = v.x * ad.x + v.y * ad.y;
    }
    for (int off = 32; off; off >>= 1) {
        ss += __shfl_xor(ss, off);
        sd += __shfl_xor(sd, off);
    }
    if (lane == 0) {
        s_src[row] = ss;
        s_dst[row] = sd;
    }
}

// ---------------- aggregation: online segment-softmax + weighted gather ----------------
// One wave per dst node. out[i] = (sum_j exp(e_j - m) * h[src_j]) / (z + 1e-16) + b

template <int C, bool RELU>
__global__ __launch_bounds__(256) void aggregate_kernel(const float* __restrict__ h,
                                                        const float* __restrict__ s_src,
                                                        const float* __restrict__ s_dst,
                                                        const int* __restrict__ row_start,
                                                        const int* __restrict__ sperm,
                                                        const float* __restrict__ bias,
                                                        float* __restrict__ out, int N) {
    constexpr int CPL = C / 64;  // channels per lane: 4 (C=256) or 2 (C=128)
    int wave = threadIdx.x >> 6, lane = threadIdx.x & 63;
    int node = blockIdx.x * 4 + wave;
    if (node >= N) return;
    int begin = row_start[node], end = row_start[node + 1];
    float sd = s_dst[node];
    float m = -INFINITY, z = 0.f;
    float acc[CPL];
#pragma unroll
    for (int u = 0; u < CPL; u++) acc[u] = 0.f;

    for (int j0 = begin; j0 < end; j0 += 64) {
        int idx = j0 + lane;
        bool valid = idx < end;
        int s = valid ? sperm[idx] : 0;
        float e = -INFINITY;
        if (valid) {
            float t = s_src[s] + sd;
            e = (t > 0.f) ? t : 0.2f * t;  // leaky_relu 0.2
        }
        float cm = e;
        for (int off = 32; off; off >>= 1) cm = fmaxf(cm, __shfl_xor(cm, off));
        float newm = fmaxf(m, cm);
        float scale = (m == -INFINITY) ? 0.f : __expf(m - newm);
        z *= scale;
#pragma unroll
        for (int u = 0; u < CPL; u++) acc[u] *= scale;
        m = newm;
        float p = valid ? __expf(e - m) : 0.f;
        float ps = p;
        for (int off = 32; off; off >>= 1) ps += __shfl_xor(ps, off);
        z += ps;
        int cnt = min(64, end - j0);
        for (int t = 0; t < cnt; t++) {
            float pt = __shfl(p, t);
            int st = __shfl(s, t);
            if constexpr (C == 256) {
                float4 v = ((const float4*)(h + (size_t)st * 256))[lane];
                acc[0] += pt * v.x;
                acc[1] += pt * v.y;
                acc[2] += pt * v.z;
                acc[3] += pt * v.w;
            } else {
                float2 v = ((const float2*)(h + (size_t)st * 128))[lane];
                acc[0] += pt * v.x;
                acc[1] += pt * v.y;
            }
        }
    }
    float inv = 1.f / (z + 1e-16f);
    if constexpr (C == 256) {
        float4 b = ((const float4*)bias)[lane];
        float4 v = make_float4(acc[0] * inv + b.x, acc[1] * inv + b.y,
                               acc[2] * inv + b.z, acc[3] * inv + b.w);
        if (RELU) {
            v.x = fmaxf(v.x, 0.f); v.y = fmaxf(v.y, 0.f);
            v.z = fmaxf(v.z, 0.f); v.w = fmaxf(v.w, 0.f);
        }
        ((float4*)(out + (size_t)node * 256))[lane] = v;
    } else {
        float2 b = ((const float2*)bias)[lane];
        float2 v = make_float2(acc[0] * inv + b.x, acc[1] * inv + b.y);
        if (RELU) { v.x = fmaxf(v.x, 0.f); v.y = fmaxf(v.y, 0.f); }
        ((float2*)(out + (size_t)node * 128))[lane] = v;
    }
}

// ---------------- launch ----------------

extern "C" void kernel_launch(void* const* d_in, const int* in_sizes, int n_in,
                              void* d_out, int out_size, void* d_ws, size_t ws_size,
                              hipStream_t stream) {
    const int N = NNODES;
    const float* x      = (const float*)d_in[0];
    const int*   ei     = (const int*)d_in[1];
    const int    E      = in_sizes[1] / 2;
    const int*   src    = ei;
    const int*   dst    = ei + E;
    const float* W1     = (const float*)d_in[2];
    const float* a_src1 = (const float*)d_in[3];
    const float* a_dst1 = (const float*)d_in[4];
    const float* b1     = (const float*)d_in[5];
    const float* W_mu   = (const float*)d_in[6];
    const float* a_src_mu = (const float*)d_in[7];
    const float* a_dst_mu = (const float*)d_in[8];
    const float* b_mu   = (const float*)d_in[9];
    const float* W_ls   = (const float*)d_in[10];
    const float* a_src_ls = (const float*)d_in[11];
    const float* a_dst_ls = (const float*)d_in[12];
    const float* b_ls   = (const float*)d_in[13];

    // workspace layout (floats)
    float* ws   = (float*)d_ws;
    float* bufA = ws;                           // N*256 : h_lin (layer1), later hmu / hls
    float* bufB = bufA + (size_t)N * 256;       // N*256 : layer-1 output h
    float* ssrc = bufB + (size_t)N * 256;       // N
    float* sdst = ssrc + N;                     // N
    int* row_start = (int*)(sdst + N);          // N+1
    int* cnt   = row_start + (N + 1);           // N (histogram, then cursor)
    int* sperm = cnt + N;                       // E

    const int egrid = (E + 255) / 256;
    const int ngrid4 = (N + 3) / 4;             // 12500
    const int mtiles = (N + 63) / 64;           // 782

    // ---- CSR build (once; shared by all 3 layers) ----
    hipMemsetAsync(cnt, 0, N * sizeof(int), stream);
    count_edges<<<egrid, 256, 0, stream>>>(dst, E, cnt);
    scan_kernel<<<1, 1024, 0, stream>>>(cnt, row_start, N);
    hipMemsetAsync(cnt, 0, N * sizeof(int), stream);
    scatter_edges<<<egrid, 256, 0, stream>>>(src, dst, E, row_start, cnt, sperm);

    // ---- layer 1: x -> h (relu), C=256 ----
    sgemm<<<dim3(mtiles, 4), 256, 0, stream>>>(x, W1, bufA, N, 256, 256);
    scores_kernel<256><<<ngrid4, 256, 0, stream>>>(bufA, a_src1, a_dst1, ssrc, sdst, N);
    aggregate_kernel<256, true><<<ngrid4, 256, 0, stream>>>(bufA, ssrc, sdst, row_start, sperm, b1, bufB, N);

    float* out_mu = (float*)d_out;
    float* out_ls = out_mu + (size_t)N * 128;

    // ---- mu head: h -> mu, C=128 (h_lin reuses bufA[0 : N*128]) ----
    sgemm<<<dim3(mtiles, 2), 256, 0, stream>>>(bufB, W_mu, bufA, N, 256, 128);
    scores_kernel<128><<<ngrid4, 256, 0, stream>>>(bufA, a_src_mu, a_dst_mu, ssrc, sdst, N);
    aggregate_kernel<128, false><<<ngrid4, 256, 0, stream>>>(bufA, ssrc, sdst, row_start, sperm, b_mu, out_mu, N);

    // ---- logstd head: h -> logstd, C=128 (h_lin at bufA[N*128 : N*256]) ----
    float* hls = bufA + (size_t)N * 128;
    sgemm<<<dim3(mtiles, 2), 256, 0, stream>>>(bufB, W_ls, hls, N, 256, 128);
    scores_kernel<128><<<ngrid4, 256, 0, stream>>>(hls, a_src_ls, a_dst_ls, ssrc, sdst, N);
    aggregate_kernel<128, false><<<ngrid4, 256, 0, stream>>>(hls, ssrc, sdst, row_start, sperm, b_ls, out_ls, N);
}

// Round 2
// 426.567 us; speedup vs baseline: 1.7978x; 1.7978x over previous
//
#include <hip/hip_runtime.h>
#include <hip/hip_bf16.h>
#include <math.h>

// ---------------------------------------------------------------------------
// VariationalGATEncoder: 3x GATConv (single head, PyG semantics).
// Round 1 -> 2 changes:
//  - GEMMs in bf16 MFMA (16x16x32), W pre-transposed so A and B frags are both
//    K-contiguous ds_read_b128 (m92-verified B^T pattern). mu/logstd GEMMs
//    fused into one Cout=256 GEMM.
//  - h / hcat stored bf16 -> halves the 800k-row random gather traffic.
//  - mu/logstd scores+aggregation fused (one pass over hcat rows).
//  - 3-kernel wave-shuffle scan instead of single-block Hillis-Steele.
// ---------------------------------------------------------------------------

#define NNODES 50000

typedef __attribute__((ext_vector_type(8))) short bf16x8;
typedef __attribute__((ext_vector_type(4))) float f32x4;

__device__ inline float bf2f(unsigned short u) {
    return __uint_as_float(((unsigned int)u) << 16);
}
__device__ inline unsigned short f2bf(float f) {
    unsigned int i = __float_as_uint(f);
    unsigned int r = i + 0x7fffu + ((i >> 16) & 1u);   // RNE
    return (unsigned short)(r >> 16);
}

// ---------------- converts ----------------

__global__ void f32_to_bf16_kernel(const float* __restrict__ in, unsigned short* __restrict__ out, int n4) {
    int i = blockIdx.x * blockDim.x + threadIdx.x;
    if (i < n4) {
        float4 v = ((const float4*)in)[i];
        ushort4 o;
        o.x = f2bf(v.x); o.y = f2bf(v.y); o.z = f2bf(v.z); o.w = f2bf(v.w);
        ((ushort4*)out)[i] = o;
    }
}

// Wt[n][k] = bf16(W[k][n]); W is [K x Nc] row-major. grid=Nc blocks, block=K threads.
__global__ void transpose_w_kernel(const float* __restrict__ W, unsigned short* __restrict__ Wt, int K, int Nc) {
    int n = blockIdx.x, k = threadIdx.x;
    Wt[(size_t)n * K + k] = f2bf(W[(size_t)k * Nc + n]);
}

// Wt (256 x 256): rows 0..127 = W_mu^T, rows 128..255 = W_ls^T. K=256, each head Nc=128.
__global__ void transpose_wcat_kernel(const float* __restrict__ Wmu, const float* __restrict__ Wls,
                                      unsigned short* __restrict__ Wt) {
    int n = blockIdx.x, k = threadIdx.x;
    float v = (n < 128) ? Wmu[(size_t)k * 128 + n] : Wls[(size_t)k * 128 + (n - 128)];
    Wt[(size_t)n * 256 + k] = f2bf(v);
}

// ---------------- CSR build ----------------

__global__ void count_edges(const int* __restrict__ dst, int E, int* __restrict__ cnt) {
    int e = blockIdx.x * blockDim.x + threadIdx.x;
    if (e < E) atomicAdd(&cnt[dst[e]], 1);
}

__global__ void scan_partial(const int* __restrict__ cnt, int* __restrict__ row_start,
                             int* __restrict__ bsum, int N) {
    __shared__ int wsum[16];
    int t = threadIdx.x;
    int gi = blockIdx.x * 1024 + t;
    int lane = t & 63, wid = t >> 6;
    int v = (gi < N) ? cnt[gi] : 0;
    int x = v;
    for (int off = 1; off < 64; off <<= 1) {
        int u = __shfl_up(x, off);
        if (lane >= off) x += u;
    }
    if (lane == 63) wsum[wid] = x;
    __syncthreads();
    if (wid == 0) {
        int s = (lane < 16) ? wsum[lane] : 0;
        for (int off = 1; off < 16; off <<= 1) {
            int u = __shfl_up(s, off);
            if (lane >= off) s += u;
        }
        if (lane < 16) wsum[lane] = s;
    }
    __syncthreads();
    int waveoff = (wid == 0) ? 0 : wsum[wid - 1];
    if (gi < N) row_start[gi] = waveoff + x - v;
    if (t == 1023) bsum[blockIdx.x] = waveoff + x;
}

__global__ void scan_bsum(int* __restrict__ bsum, int nb) {   // one wave, nb <= 64
    int lane = threadIdx.x;
    int v = (lane < nb) ? bsum[lane] : 0;
    int x = v;
    for (int off = 1; off < 64; off <<= 1) {
        int u = __shfl_up(x, off);
        if (lane >= off) x += u;
    }
    if (lane < nb) bsum[lane] = x - v;   // exclusive
}

__global__ void scan_add(int* __restrict__ row_start, const int* __restrict__ bsum, int N, int E) {
    int gi = blockIdx.x * 1024 + threadIdx.x;
    if (gi < N) row_start[gi] += bsum[blockIdx.x];
    if (gi == 0) row_start[N] = E;
}

__global__ void scatter_edges(const int* __restrict__ src, const int* __restrict__ dst, int E,
                              const int* __restrict__ row_start, int* __restrict__ cursor,
                              int* __restrict__ sperm) {
    int e = blockIdx.x * blockDim.x + threadIdx.x;
    if (e < E) {
        int d = dst[e];
        int pos = row_start[d] + atomicAdd(&cursor[d], 1);
        sperm[pos] = src[e];
    }
}

// ---------------- bf16 MFMA GEMM ----------------
// C[M,Cout](bf16) = A[M,K](bf16) @ Bt[Cout,K](bf16)^T, fp32 accumulate.
// 128x128 tile, BK=32, 256 threads (4 waves, 2x2 of 64x64 each).

__global__ __launch_bounds__(256) void mfma_gemm(const unsigned short* __restrict__ A,
                                                 const unsigned short* __restrict__ Bt,
                                                 unsigned short* __restrict__ C_,
                                                 int M, int K, int Cout) {
    __shared__ __align__(16) unsigned short As[128 * 40];  // rows padded to 40 (80B): 2-way max
    __shared__ __align__(16) unsigned short Bs[128 * 40];
    int t = threadIdx.x;
    int lane = t & 63, w = t >> 6;
    int wm = w & 1, wn = w >> 1;
    int l15 = lane & 15, quad = lane >> 4;
    int mbase = blockIdx.x * 128, nbase = blockIdx.y * 128;

    f32x4 acc[4][4];
    const f32x4 zero = {0.f, 0.f, 0.f, 0.f};
#pragma unroll
    for (int mt = 0; mt < 4; mt++)
#pragma unroll
        for (int nt = 0; nt < 4; nt++) acc[mt][nt] = zero;

    for (int k0 = 0; k0 < K; k0 += 32) {
#pragma unroll
        for (int i = t; i < 512; i += 256) {
            int row = i >> 2, seg = i & 3;
            int gr = mbase + row;
            float4 va = make_float4(0.f, 0.f, 0.f, 0.f);
            if (gr < M) va = *(const float4*)(A + (size_t)gr * K + k0 + seg * 8);
            *(float4*)(&As[row * 40 + seg * 8]) = va;
            float4 vb = *(const float4*)(Bt + (size_t)(nbase + row) * K + k0 + seg * 8);
            *(float4*)(&Bs[row * 40 + seg * 8]) = vb;
        }
        __syncthreads();
        bf16x8 af[4], bfr[4];
#pragma unroll
        for (int mt = 0; mt < 4; mt++)
            af[mt] = *(const bf16x8*)(&As[(wm * 64 + mt * 16 + l15) * 40 + quad * 8]);
#pragma unroll
        for (int nt = 0; nt < 4; nt++)
            bfr[nt] = *(const bf16x8*)(&Bs[(wn * 64 + nt * 16 + l15) * 40 + quad * 8]);
#pragma unroll
        for (int mt = 0; mt < 4; mt++)
#pragma unroll
            for (int nt = 0; nt < 4; nt++)
                acc[mt][nt] = __builtin_amdgcn_mfma_f32_16x16x32_bf16(af[mt], bfr[nt], acc[mt][nt], 0, 0, 0);
        __syncthreads();
    }
    // epilogue: C/D layout col=lane&15, row=quad*4+reg (m89-verified)
#pragma unroll
    for (int mt = 0; mt < 4; mt++) {
#pragma unroll
        for (int nt = 0; nt < 4; nt++) {
#pragma unroll
            for (int r = 0; r < 4; r++) {
                int m = mbase + wm * 64 + mt * 16 + quad * 4 + r;
                int n = nbase + wn * 64 + nt * 16 + l15;
                if (m < M) C_[(size_t)m * Cout + n] = f2bf(acc[mt][nt][r]);
            }
        }
    }
}

// ---------------- scores ----------------

__global__ __launch_bounds__(256) void scores_l1(const unsigned short* __restrict__ h,
                                                 const float* __restrict__ a_src,
                                                 const float* __restrict__ a_dst,
                                                 float* __restrict__ ssrc,
                                                 float* __restrict__ sdst, int N) {
    int wave = threadIdx.x >> 6, lane = threadIdx.x & 63;
    int row = blockIdx.x * 4 + wave;
    if (row >= N) return;
    ushort4 u = *(const ushort4*)(h + (size_t)row * 256 + lane * 4);
    float h0 = bf2f(u.x), h1 = bf2f(u.y), h2 = bf2f(u.z), h3 = bf2f(u.w);
    float4 av = ((const float4*)a_src)[lane];
    float4 dv = ((const float4*)a_dst)[lane];
    float ss = h0 * av.x + h1 * av.y + h2 * av.z + h3 * av.w;
    float sd = h0 * dv.x + h1 * dv.y + h2 * dv.z + h3 * dv.w;
    for (int off = 32; off; off >>= 1) {
        ss += __shfl_xor(ss, off);
        sd += __shfl_xor(sd, off);
    }
    if (lane == 0) {
        ssrc[row] = ss;
        sdst[row] = sd;
    }
}

// lanes 0..31 -> mu head (channels lane*4..+3), lanes 32..63 -> logstd head.
__global__ __launch_bounds__(256) void scores_cat(const unsigned short* __restrict__ hcat,
                                                  const float* __restrict__ a_src_mu, const float* __restrict__ a_dst_mu,
                                                  const float* __restrict__ a_src_ls, const float* __restrict__ a_dst_ls,
                                                  float* __restrict__ sm_s, float* __restrict__ sm_d,
                                                  float* __restrict__ sl_s, float* __restrict__ sl_d, int N) {
    int wave = threadIdx.x >> 6, lane = threadIdx.x & 63;
    int row = blockIdx.x * 4 + wave;
    if (row >= N) return;
    ushort4 u = *(const ushort4*)(hcat + (size_t)row * 256 + lane * 4);
    float h0 = bf2f(u.x), h1 = bf2f(u.y), h2 = bf2f(u.z), h3 = bf2f(u.w);
    bool isMu = lane < 32;
    const float* as = isMu ? a_src_mu : a_src_ls;
    const float* ad = isMu ? a_dst_mu : a_dst_ls;
    int c = (lane & 31) * 4;
    float4 av = *(const float4*)(as + c);
    float4 dv = *(const float4*)(ad + c);
    float ss = h0 * av.x + h1 * av.y + h2 * av.z + h3 * av.w;
    float sd = h0 * dv.x + h1 * dv.y + h2 * dv.z + h3 * dv.w;
    for (int off = 16; off; off >>= 1) {   // reduce within each 32-lane half
        ss += __shfl_xor(ss, off);
        sd += __shfl_xor(sd, off);
    }
    if ((lane & 31) == 0) {
        if (isMu) { sm_s[row] = ss; sm_d[row] = sd; }
        else      { sl_s[row] = ss; sl_d[row] = sd; }
    }
}

// ---------------- aggregation ----------------
// layer 1: one wave per dst node, online softmax, bf16 row gather (512B/row),
// output bf16 (feeds GEMM-2), relu + bias.

__global__ __launch_bounds__(256) void aggregate_l1(const unsigned short* __restrict__ h,
                                                    const float* __restrict__ s_src,
                                                    const float* __restrict__ s_dst,
                                                    const int* __restrict__ row_start,
                                                    const int* __restrict__ sperm,
                                                    const float* __restrict__ bias,
                                                    unsigned short* __restrict__ out, int N) {
    int wave = threadIdx.x >> 6, lane = threadIdx.x & 63;
    int node = blockIdx.x * 4 + wave;
    if (node >= N) return;
    int begin = row_start[node], end = row_start[node + 1];
    float sd = s_dst[node];
    float m = -INFINITY, z = 0.f;
    float acc0 = 0.f, acc1 = 0.f, acc2 = 0.f, acc3 = 0.f;

    for (int j0 = begin; j0 < end; j0 += 64) {
        int idx = j0 + lane;
        bool valid = idx < end;
        int s = valid ? sperm[idx] : 0;
        float e = -INFINITY;
        if (valid) {
            float t = s_src[s] + sd;
            e = (t > 0.f) ? t : 0.2f * t;
        }
        float cm = e;
        for (int off = 32; off; off >>= 1) cm = fmaxf(cm, __shfl_xor(cm, off));
        float newm = fmaxf(m, cm);
        float scale = (m == -INFINITY) ? 0.f : __expf(m - newm);
        z *= scale;
        acc0 *= scale; acc1 *= scale; acc2 *= scale; acc3 *= scale;
        m = newm;
        float p = valid ? __expf(e - m) : 0.f;
        float ps = p;
        for (int off = 32; off; off >>= 1) ps += __shfl_xor(ps, off);
        z += ps;
        int cnt = min(64, end - j0);
        for (int t = 0; t < cnt; t++) {
            float pt = __shfl(p, t);
            int st = __shfl(s, t);
            ushort4 u = *(const ushort4*)(h + (size_t)st * 256 + lane * 4);
            acc0 += pt * bf2f(u.x);
            acc1 += pt * bf2f(u.y);
            acc2 += pt * bf2f(u.z);
            acc3 += pt * bf2f(u.w);
        }
    }
    float inv = 1.f / (z + 1e-16f);
    float4 bv = ((const float4*)bias)[lane];
    float o0 = fmaxf(acc0 * inv + bv.x, 0.f);
    float o1 = fmaxf(acc1 * inv + bv.y, 0.f);
    float o2 = fmaxf(acc2 * inv + bv.z, 0.f);
    float o3 = fmaxf(acc3 * inv + bv.w, 0.f);
    ushort4 o;
    o.x = f2bf(o0); o.y = f2bf(o1); o.z = f2bf(o2); o.w = f2bf(o3);
    *(ushort4*)(out + (size_t)node * 256 + lane * 4) = o;
}

// fused mu/logstd: lanes 0..31 accumulate mu channels, 32..63 logstd channels.
// Each lane computes edge weights for BOTH heads (per-edge), state kept per head.
__global__ __launch_bounds__(256) void aggregate_cat(const unsigned short* __restrict__ hcat,
                                                     const float* __restrict__ sm_s, const float* __restrict__ sm_d,
                                                     const float* __restrict__ sl_s, const float* __restrict__ sl_d,
                                                     const int* __restrict__ row_start,
                                                     const int* __restrict__ sperm,
                                                     const float* __restrict__ b_mu, const float* __restrict__ b_ls,
                                                     float* __restrict__ out_mu, float* __restrict__ out_ls, int N) {
    int wave = threadIdx.x >> 6, lane = threadIdx.x & 63;
    int node = blockIdx.x * 4 + wave;
    if (node >= N) return;
    int begin = row_start[node], end = row_start[node + 1];
    float sdm = sm_d[node], sdl = sl_d[node];
    float mM = -INFINITY, zM = 0.f, mL = -INFINITY, zL = 0.f;
    float acc0 = 0.f, acc1 = 0.f, acc2 = 0.f, acc3 = 0.f;
    bool isMu = lane < 32;

    for (int j0 = begin; j0 < end; j0 += 64) {
        int idx = j0 + lane;
        bool valid = idx < end;
        int s = valid ? sperm[idx] : 0;
        float eM = -INFINITY, eL = -INFINITY;
        if (valid) {
            float tM = sm_s[s] + sdm;
            eM = (tM > 0.f) ? tM : 0.2f * tM;
            float tL = sl_s[s] + sdl;
            eL = (tL > 0.f) ? tL : 0.2f * tL;
        }
        float cmM = eM, cmL = eL;
        for (int off = 32; off; off >>= 1) {
            cmM = fmaxf(cmM, __shfl_xor(cmM, off));
            cmL = fmaxf(cmL, __shfl_xor(cmL, off));
        }
        float nmM = fmaxf(mM, cmM);
        float nmL = fmaxf(mL, cmL);
        float scM = (mM == -INFINITY) ? 0.f : __expf(mM - nmM);
        float scL = (mL == -INFINITY) ? 0.f : __expf(mL - nmL);
        zM *= scM; zL *= scL;
        mM = nmM; mL = nmL;
        float mysc = isMu ? scM : scL;
        acc0 *= mysc; acc1 *= mysc; acc2 *= mysc; acc3 *= mysc;
        float pM = valid ? __expf(eM - mM) : 0.f;
        float pL = valid ? __expf(eL - mL) : 0.f;
        float psM = pM, psL = pL;
        for (int off = 32; off; off >>= 1) {
            psM += __shfl_xor(psM, off);
            psL += __shfl_xor(psL, off);
        }
        zM += psM; zL += psL;
        int cnt = min(64, end - j0);
        for (int t = 0; t < cnt; t++) {
            float ptM = __shfl(pM, t);
            float ptL = __shfl(pL, t);
            int st = __shfl(s, t);
            float pt = isMu ? ptM : ptL;
            ushort4 u = *(const ushort4*)(hcat + (size_t)st * 256 + lane * 4);
            acc0 += pt * bf2f(u.x);
            acc1 += pt * bf2f(u.y);
            acc2 += pt * bf2f(u.z);
            acc3 += pt * bf2f(u.w);
        }
    }
    float inv = isMu ? (1.f / (zM + 1e-16f)) : (1.f / (zL + 1e-16f));
    int c = (lane & 31) * 4;
    float4 bv = *(const float4*)((isMu ? b_mu : b_ls) + c);
    float4 o = make_float4(acc0 * inv + bv.x, acc1 * inv + bv.y,
                           acc2 * inv + bv.z, acc3 * inv + bv.w);
    float* dstp = isMu ? (out_mu + (size_t)node * 128 + c) : (out_ls + (size_t)node * 128 + c);
    *(float4*)dstp = o;
}

// ---------------- launch ----------------

extern "C" void kernel_launch(void* const* d_in, const int* in_sizes, int n_in,
                              void* d_out, int out_size, void* d_ws, size_t ws_size,
                              hipStream_t stream) {
    const int N = NNODES;
    const float* x      = (const float*)d_in[0];
    const int*   ei     = (const int*)d_in[1];
    const int    E      = in_sizes[1] / 2;
    const int*   src    = ei;
    const int*   dst    = ei + E;
    const float* W1     = (const float*)d_in[2];
    const float* a_src1 = (const float*)d_in[3];
    const float* a_dst1 = (const float*)d_in[4];
    const float* b1     = (const float*)d_in[5];
    const float* W_mu   = (const float*)d_in[6];
    const float* a_src_mu = (const float*)d_in[7];
    const float* a_dst_mu = (const float*)d_in[8];
    const float* b_mu   = (const float*)d_in[9];
    const float* W_ls   = (const float*)d_in[10];
    const float* a_src_ls = (const float*)d_in[11];
    const float* a_dst_ls = (const float*)d_in[12];
    const float* b_ls   = (const float*)d_in[13];

    const size_t NM = (size_t)N * 256;   // 12.8M elems

    // workspace layout
    char* w = (char*)d_ws;
    unsigned short* xb   = (unsigned short*)w;              w += NM * 2;
    unsigned short* hlin = (unsigned short*)w;              w += NM * 2;
    unsigned short* h    = (unsigned short*)w;              w += NM * 2;
    unsigned short* hcat = (unsigned short*)w;              w += NM * 2;
    unsigned short* W1t  = (unsigned short*)w;              w += 256 * 256 * 2;
    unsigned short* Wct  = (unsigned short*)w;              w += 256 * 256 * 2;
    float* s1s = (float*)w;  w += N * 4;
    float* s1d = (float*)w;  w += N * 4;
    float* sms = (float*)w;  w += N * 4;
    float* smd = (float*)w;  w += N * 4;
    float* sls = (float*)w;  w += N * 4;
    float* sld = (float*)w;  w += N * 4;
    int* row_start = (int*)w;  w += (N + 1) * 4;
    int* cnt = (int*)w;        w += N * 4;
    int* bsum = (int*)w;       w += 64 * 4;
    int* sperm = (int*)w;      w += (size_t)E * 4;

    const int egrid = (E + 255) / 256;
    const int ngrid4 = (N + 3) / 4;               // 12500
    const int nb1024 = (N + 1023) / 1024;         // 49
    const int mtiles = (N + 127) / 128;           // 391

    // ---- converts ----
    f32_to_bf16_kernel<<<(int)((NM / 4 + 255) / 256), 256, 0, stream>>>(x, xb, (int)(NM / 4));
    transpose_w_kernel<<<256, 256, 0, stream>>>(W1, W1t, 256, 256);
    transpose_wcat_kernel<<<256, 256, 0, stream>>>(W_mu, W_ls, Wct);

    // ---- CSR build (once; shared by all 3 layers) ----
    hipMemsetAsync(cnt, 0, N * sizeof(int), stream);
    count_edges<<<egrid, 256, 0, stream>>>(dst, E, cnt);
    scan_partial<<<nb1024, 1024, 0, stream>>>(cnt, row_start, bsum, N);
    scan_bsum<<<1, 64, 0, stream>>>(bsum, nb1024);
    scan_add<<<nb1024, 1024, 0, stream>>>(row_start, bsum, N, E);
    hipMemsetAsync(cnt, 0, N * sizeof(int), stream);
    scatter_edges<<<egrid, 256, 0, stream>>>(src, dst, E, row_start, cnt, sperm);

    // ---- layer 1: x -> h (relu) ----
    mfma_gemm<<<dim3(mtiles, 2), 256, 0, stream>>>(xb, W1t, hlin, N, 256, 256);
    scores_l1<<<ngrid4, 256, 0, stream>>>(hlin, a_src1, a_dst1, s1s, s1d, N);
    aggregate_l1<<<ngrid4, 256, 0, stream>>>(hlin, s1s, s1d, row_start, sperm, b1, h, N);

    // ---- fused mu/logstd head ----
    mfma_gemm<<<dim3(mtiles, 2), 256, 0, stream>>>(h, Wct, hcat, N, 256, 256);
    scores_cat<<<ngrid4, 256, 0, stream>>>(hcat, a_src_mu, a_dst_mu, a_src_ls, a_dst_ls,
                                           sms, smd, sls, sld, N);
    float* out_mu = (float*)d_out;
    float* out_ls = out_mu + (size_t)N * 128;
    aggregate_cat<<<ngrid4, 256, 0, stream>>>(hcat, sms, smd, sls, sld, row_start, sperm,
                                              b_mu, b_ls, out_mu, out_ls, N);
}